// Round 3
// baseline (717.238 us; speedup 1.0000x reference)
//
#include <hip/hip_runtime.h>
#include <stdint.h>

// Problem constants
#define BB 16384
#define II 512
#define HH 1024
#define OO 512

typedef short s16x8 __attribute__((ext_vector_type(8)));
typedef float f32x4 __attribute__((ext_vector_type(4)));

__device__ __forceinline__ unsigned short f2bf(float x) {
  union { float f; unsigned u; } v; v.f = x;
  return (unsigned short)((v.u + 0x7fffu + ((v.u >> 16) & 1u)) >> 16);  // RNE
}
__device__ __forceinline__ float bf2f(unsigned short b) {
  union { unsigned u; float f; } v; v.u = ((unsigned)b) << 16;
  return v.f;
}
__device__ __forceinline__ float sigmoid_f(float x) {
  return 1.0f / (1.0f + __expf(-x));
}
__device__ __forceinline__ float tanh_f(float x) {
  float ax = fabsf(x);
  float e = __expf(-2.0f * ax);
  float t = (1.0f - e) / (1.0f + e);
  return x >= 0.0f ? t : -t;
}

// async global->LDS, 16B per lane, LDS dest = wave-uniform base + lane*16
__device__ __forceinline__ void stage16(const void* g, void* l) {
  __builtin_amdgcn_global_load_lds((const __attribute__((address_space(1))) void*)g,
                                   (__attribute__((address_space(3))) void*)l,
                                   16, 0, 0);
}

// ---- 128-tile helper (kept for gemm_out) ----
__device__ __forceinline__ void mma_step64(const unsigned short* As, const unsigned short* Bs,
                                           f32x4 acc[4][4], int lane, int wave) {
  const int wm = wave & 1, wn = wave >> 1;
  const int ln = lane & 15, q = lane >> 4;
#pragma unroll
  for (int s = 0; s < 2; ++s) {
    s16x8 af[4], bfr[4];
#pragma unroll
    for (int i = 0; i < 4; ++i) {
      const int r = wm * 64 + i * 16 + ln;
      af[i] = *(const s16x8*)(As + r * 64 + ((((s << 2) + q) + r) & 7) * 8);
    }
#pragma unroll
    for (int i = 0; i < 4; ++i) {
      const int r = wn * 64 + i * 16 + ln;
      bfr[i] = *(const s16x8*)(Bs + r * 64 + ((((s << 2) + q) + r) & 7) * 8);
    }
#pragma unroll
    for (int mi = 0; mi < 4; ++mi)
#pragma unroll
      for (int ni = 0; ni < 4; ++ni)
        acc[mi][ni] = __builtin_amdgcn_mfma_f32_16x16x32_bf16(af[mi], bfr[ni], acc[mi][ni], 0, 0, 0);
  }
}

// ---------------- prep kernels ----------------

__global__ __launch_bounds__(256) void prep_X(const float* __restrict__ inp,
                                              const float* __restrict__ h,
                                              unsigned short* __restrict__ Xb,
                                              unsigned short* __restrict__ Hlo) {
  int t = blockIdx.x * 256 + threadIdx.x;
  int base = t * 8;
  int b = base / 1536;
  int k = base - b * 1536;
  const float* src = (k < 512) ? (inp + b * 512 + k) : (h + b * 1024 + (k - 512));
  float4 v0 = *(const float4*)src;
  float4 v1 = *(const float4*)(src + 4);
  float f[8] = {v0.x, v0.y, v0.z, v0.w, v1.x, v1.y, v1.z, v1.w};
  unsigned short hi[8];
#pragma unroll
  for (int i = 0; i < 8; ++i) hi[i] = f2bf(f[i]);
  *(s16x8*)(Xb + base) = *(s16x8*)hi;
  if (k >= 512) {
    unsigned short lo[8];
#pragma unroll
    for (int i = 0; i < 8; ++i) lo[i] = f2bf(f[i] - bf2f(hi[i]));
    *(s16x8*)(Hlo + b * 1024 + (k - 512)) = *(s16x8*)lo;
  }
}

// Gate weights -> bf16 [4096][1536], K-contiguous, columns permuted for BN=256:
// n = blkX*256 + wn*64 + gate*16 + ln  <->  unit = blkX*64 + wn*16 + ln
__global__ __launch_bounds__(256) void prep_Wg(const float* __restrict__ Wx,
                                               const float* __restrict__ Wh,
                                               unsigned short* __restrict__ Wg) {
  int t = blockIdx.x * 256 + threadIdx.x;
  int base = t * 8;
  int n = base / 1536;
  int k = base - n * 1536;
  int r = n & 255;
  int gate = (r >> 4) & 3;
  int unit = ((n >> 8) << 6) + (((r >> 6) & 3) << 4) + (r & 15);
  const float* src = (k < 512) ? (Wx + (gate * 1024 + unit) * 512 + k)
                               : (Wh + (gate * 1024 + unit) * 1024 + (k - 512));
  float4 v0 = *(const float4*)src;
  float4 v1 = *(const float4*)(src + 4);
  float f[8] = {v0.x, v0.y, v0.z, v0.w, v1.x, v1.y, v1.z, v1.w};
  unsigned short o[8];
#pragma unroll
  for (int i = 0; i < 8; ++i) o[i] = f2bf(f[i]);
  *(s16x8*)(Wg + base) = *(s16x8*)o;
}

// z-correction weights [1024][2048]: k<1024 -> W_lo(Whz), k>=1024 -> W_hi(Whz)
__global__ __launch_bounds__(256) void prep_Wz2(const float* __restrict__ Whz,
                                                unsigned short* __restrict__ Wz2) {
  int t = blockIdx.x * 256 + threadIdx.x;
  int base = t * 8;
  int n = base >> 11;
  int k = base & 2047;
  int klo = (k < 1024) ? k : (k - 1024);
  const float* src = Whz + n * 1024 + klo;
  float4 v0 = *(const float4*)src;
  float4 v1 = *(const float4*)(src + 4);
  float f[8] = {v0.x, v0.y, v0.z, v0.w, v1.x, v1.y, v1.z, v1.w};
  unsigned short o[8];
  if (k < 1024) {
#pragma unroll
    for (int i = 0; i < 8; ++i) { unsigned short h_ = f2bf(f[i]); o[i] = f2bf(f[i] - bf2f(h_)); }
  } else {
#pragma unroll
    for (int i = 0; i < 8; ++i) o[i] = f2bf(f[i]);
  }
  *(s16x8*)(Wz2 + base) = *(s16x8*)o;
}

__global__ __launch_bounds__(256) void prep_Wout(const float* __restrict__ Wout,
                                                 unsigned short* __restrict__ Wo) {
  int t = blockIdx.x * 256 + threadIdx.x;
  int base = t * 8;
  float4 v0 = *(const float4*)(Wout + base);
  float4 v1 = *(const float4*)(Wout + base + 4);
  float f[8] = {v0.x, v0.y, v0.z, v0.w, v1.x, v1.y, v1.z, v1.w};
  unsigned short o[8];
#pragma unroll
  for (int i = 0; i < 8; ++i) o[i] = f2bf(f[i]);
  *(s16x8*)(Wo + base) = *(s16x8*)o;
}

// ========== 256x256 / 8-wave software-pipelined GEMM (balanced 4-phase) ==========
//
// LDS: lds[buf][A/B][256*64 bf16]; chunk-rotation swizzle (slot=(j+row)&7),
// conflict-free (measured 0). 1 block/CU (128 KiB LDS), 2 waves/SIMD.
//
// Per-phase ds_read load is balanced (4/4/8/8) and reads are issued ONE PHASE
// AHEAD of their consuming MFMA, so every lgkm wait is counted (excludes the
// just-issued reads) and covers reads a full phase old => ~zero exposed LDS
// latency. Tile t (cur=t&1):
//  q0: read A(t)quad1->aN; stage A(t+1)->dA[cur^1];  [bar; lgkm(4); MFMA q0(aC); bar]
//  q1: read A(t)quad2->aC; stage B(t+2)->dB[cur];    [bar; lgkm(4); MFMA q1(aN)]; vmcnt(8); bar
//  q2: read A(t)quad3->aN + B(t+1)ks0->bqN;          [bar; lgkm(8); MFMA q2(aC)]; vmcnt(4); bar
//  q3: read B(t+1)ks1->bqN + A(t+1)quad0->aC;        [bar; lgkm(8); MFMA q3(aN); bar]
// vmcnt(8)@q1-end certifies B(t+1) (staged 4 phases earlier, outstanding-newer =
// A(t+1)+B(t+2) = 8) before q2's B reads; vmcnt(4)@q2-end certifies A(t+1)
// (outstanding-newer = B(t+2) = 4) before q3's A reads. Both waits are on loads
// >=2 phases old => ~free. Staging hazards: buffer's last ds_reads are always
// certified by the preceding phase's counted lgkm + barrier before overwrite.

#define RD_A(CA, MI, KS) (*(const s16x8*)((CA) + ((KS) ? aoff1 : aoff0) + (MI) * 1024))
#define RD_B(CB, NI, KS) (*(const s16x8*)((CB) + ((KS) ? boff1 : boff0) + (NI) * 1024))
#define VM8 asm volatile("s_waitcnt vmcnt(8)" ::: "memory")
#define VM4 asm volatile("s_waitcnt vmcnt(4)" ::: "memory")
#define VM0 asm volatile("s_waitcnt vmcnt(0)" ::: "memory")
#define LGKM8 asm volatile("s_waitcnt lgkmcnt(8)" ::: "memory")
#define LGKM4 asm volatile("s_waitcnt lgkmcnt(4)" ::: "memory")
#define LGKM0 asm volatile("s_waitcnt lgkmcnt(0)" ::: "memory")
#define BARR __builtin_amdgcn_s_barrier()
#define VMNONE ((void)0)
#define NOST ((void)0)

// read one A quadrant (rows 2Q*16..(2Q+2)*16), both k-slices, into slot S[4]
#define AQ(S, CA, Q) do { \
  S[0] = RD_A(CA, 2 * (Q), 0);  S[1] = RD_A(CA, 2 * (Q) + 1, 0); \
  S[2] = RD_A(CA, 2 * (Q), 1);  S[3] = RD_A(CA, 2 * (Q) + 1, 1); } while (0)
// read one B k-slice half into BQ[4*KS..4*KS+3]
#define BH(BQ, CB, KS) do { \
  BQ[4 * (KS) + 0] = RD_B(CB, 0, KS); BQ[4 * (KS) + 1] = RD_B(CB, 1, KS); \
  BQ[4 * (KS) + 2] = RD_B(CB, 2, KS); BQ[4 * (KS) + 3] = RD_B(CB, 3, KS); } while (0)

#define ST_A2(TT, DB) do { \
  stage16(gA[0][0] + (size_t)(TT) * 64, (DB)); \
  stage16(gA[0][1] + (size_t)(TT) * 64, (DB) + 4096); \
  stage16(gA[1][0] + (size_t)(TT) * 64, (DB) + 8192); \
  stage16(gA[1][1] + (size_t)(TT) * 64, (DB) + 12288); } while (0)
#define ST_B2(TT, DB) do { \
  stage16(gB[0][0] + (size_t)(TT) * 64, (DB)); \
  stage16(gB[0][1] + (size_t)(TT) * 64, (DB) + 4096); \
  stage16(gB[1][0] + (size_t)(TT) * 64, (DB) + 8192); \
  stage16(gB[1][1] + (size_t)(TT) * 64, (DB) + 12288); } while (0)
// zcorr A source switches at tile 16 (h_hi from Xb, then h_lo from Hlo)
#define ZST_A2(TT, DB) do { \
  const unsigned short *z0_, *z1_, *z2_, *z3_; \
  if ((TT) < 16) { \
    z0_ = gAX[0][0] + (size_t)(TT) * 64; z1_ = gAX[0][1] + (size_t)(TT) * 64; \
    z2_ = gAX[1][0] + (size_t)(TT) * 64; z3_ = gAX[1][1] + (size_t)(TT) * 64; \
  } else { \
    const int tz_ = (TT) - 16; \
    z0_ = gAH[0][0] + (size_t)tz_ * 64; z1_ = gAH[0][1] + (size_t)tz_ * 64; \
    z2_ = gAH[1][0] + (size_t)tz_ * 64; z3_ = gAH[1][1] + (size_t)tz_ * 64; \
  } \
  stage16(z0_, (DB)); stage16(z1_, (DB) + 4096); \
  stage16(z2_, (DB) + 8192); stage16(z3_, (DB) + 12288); } while (0)

// MFMA for output quadrant Q (acc rows 2Q,2Q+1) from A-slot S and B regs BQ
#define PH(Q, WAITM, S, BQ) do { \
  __builtin_amdgcn_s_barrier(); \
  WAITM; \
  __builtin_amdgcn_sched_barrier(0); \
  __builtin_amdgcn_s_setprio(1); \
  _Pragma("unroll") \
  for (int ni = 0; ni < 4; ++ni) { \
    acc[2 * (Q)    ][ni] = __builtin_amdgcn_mfma_f32_16x16x32_bf16(S[0], BQ[ni], acc[2 * (Q)    ][ni], 0, 0, 0); \
    acc[2 * (Q) + 1][ni] = __builtin_amdgcn_mfma_f32_16x16x32_bf16(S[1], BQ[ni], acc[2 * (Q) + 1][ni], 0, 0, 0); \
  } \
  _Pragma("unroll") \
  for (int ni = 0; ni < 4; ++ni) { \
    acc[2 * (Q)    ][ni] = __builtin_amdgcn_mfma_f32_16x16x32_bf16(S[2], BQ[4 + ni], acc[2 * (Q)    ][ni], 0, 0, 0); \
    acc[2 * (Q) + 1][ni] = __builtin_amdgcn_mfma_f32_16x16x32_bf16(S[3], BQ[4 + ni], acc[2 * (Q) + 1][ni], 0, 0, 0); \
  } \
  __builtin_amdgcn_s_setprio(0); \
} while (0)

// Standard pipelined tile. CA: cur A lds; CAn: next A lds; CBn: next B lds;
// BQC: cur B regs; BQN: next B regs. AST at q0, BST at q1.
#define KT_STD(CA, CAn, CBn, BQC, BQN, AST, BST, VMQ1, VMQ2) do { \
  AQ(aN, CA, 1); AST; \
  PH(0, LGKM4, aC, BQC); BARR; \
  AQ(aC, CA, 2); BST; \
  PH(1, LGKM4, aN, BQC); VMQ1; BARR; \
  AQ(aN, CA, 3); BH(BQN, CBn, 0); \
  PH(2, LGKM8, aC, BQC); VMQ2; BARR; \
  BH(BQN, CBn, 1); AQ(aC, CAn, 0); \
  PH(3, LGKM8, aN, BQC); BARR; \
} while (0)

// Final tile: no next-tile reads, no staging.
#define KT_LAST(CA, BQC) do { \
  AQ(aN, CA, 1); \
  PH(0, LGKM4, aC, BQC); BARR; \
  AQ(aC, CA, 2); \
  PH(1, LGKM4, aN, BQC); BARR; \
  AQ(aN, CA, 3); \
  PH(2, LGKM4, aC, BQC); BARR; \
  PH(3, LGKM0, aN, BQC); \
} while (0)

// Gate GEMM + fused LSTM epilogue. M=16384, N=4096 (permuted), K=1536, NT=24.
__global__ __launch_bounds__(512, 2) void gemm_gates2(const unsigned short* __restrict__ Xb,
                                                      const unsigned short* __restrict__ Wg,
                                                      const float* __restrict__ bx,
                                                      const float* __restrict__ cold,
                                                      const unsigned short* __restrict__ Dgz,
                                                      float* __restrict__ hnew,
                                                      unsigned short* __restrict__ hnewb) {
  __shared__ unsigned short lds[2][2][16384];   // 128 KiB
  const int tid = threadIdx.x;
  const int lane = tid & 63, wave = tid >> 6;
  const int wm = wave & 1, wn = wave >> 1;
  const int ln = lane & 15, qlane = lane >> 4;
  // natural mapping: bx mod 8 pins each XCD to 2 B-panels (L2-resident)
  const int n0 = blockIdx.x << 8, m0 = blockIdx.y << 8;
  const int sr = tid >> 3;
  const int j = ((tid & 7) - (sr & 7)) & 7;

  const unsigned short* gA[2][2];
  const unsigned short* gB[2][2];
#pragma unroll
  for (int hh = 0; hh < 2; ++hh)
#pragma unroll
    for (int u = 0; u < 2; ++u) {
      const int row = hh * 128 + u * 64 + sr;
      gA[hh][u] = Xb + (size_t)(m0 + row) * 1536 + j * 8;
      gB[hh][u] = Wg + (size_t)(n0 + row) * 1536 + j * 8;
    }
  unsigned short* const dA0 = &lds[0][0][0] + (tid & ~63) * 8;
  unsigned short* const dB0 = &lds[0][1][0] + (tid & ~63) * 8;
  unsigned short* const dA1 = &lds[1][0][0] + (tid & ~63) * 8;
  unsigned short* const dB1 = &lds[1][1][0] + (tid & ~63) * 8;
  const unsigned short* const lA0 = &lds[0][0][0];
  const unsigned short* const lB0 = &lds[0][1][0];
  const unsigned short* const lA1 = &lds[1][0][0];
  const unsigned short* const lB1 = &lds[1][1][0];
  const int sl0 = ((qlane + ln) & 7) * 8;
  const int sl1 = sl0 ^ 32;
  const int aoff0 = (wm * 128 + ln) * 64 + sl0;
  const int aoff1 = (wm * 128 + ln) * 64 + sl1;
  const int boff0 = (wn * 64 + ln) * 64 + sl0;
  const int boff1 = (wn * 64 + ln) * 64 + sl1;

  f32x4 acc[8][4] = {};
  s16x8 aC[4], aN[4], bqA[8], bqB[8];

  // prologue: stage tiles 0 and 1; wait tile 0; preload B(0) + A(0)q0
  ST_A2(0, dA0); ST_B2(0, dB0);
  ST_A2(1, dA1); ST_B2(1, dB1);
  VM8;
  BARR;
  BH(bqA, lB0, 0); BH(bqA, lB0, 1);
  AQ(aC, lA0, 0);

  // tile 0: A(1) already staged; vmcnt(4)@q1 certifies A(1),B(1)
  KT_STD(lA0, lA1, lB1, bqA, bqB, NOST, ST_B2(2, dB0), VM4, VM4);
#pragma unroll 1
  for (int t = 1; t < 21; t += 2) {
    KT_STD(lA1, lA0, lB0, bqB, bqA, ST_A2(t + 1, dA0), ST_B2(t + 2, dB1), VM8, VM4);
    KT_STD(lA0, lA1, lB1, bqA, bqB, ST_A2(t + 2, dA1), ST_B2(t + 3, dB0), VM8, VM4);
  }
  KT_STD(lA1, lA0, lB0, bqB, bqA, ST_A2(22, dA0), ST_B2(23, dB1), VM8, VM4);  // tile 21
  KT_STD(lA0, lA1, lB1, bqA, bqB, ST_A2(23, dA1), NOST, VM4, VM0);            // tile 22
  KT_LAST(lA1, bqB);                                                          // tile 23

  // Epilogue: acc[mi][ni] is gate ni for unit = blkX*64 + wn*16 + ln.
  const int unit = ((int)blockIdx.x << 6) + (wn << 4) + ln;
  const float bi = bx[unit];
  const float bo = bx[1024 + unit];
  const float bfg = bx[2048 + unit];
  const float bz = bx[3072 + unit];
#pragma unroll
  for (int mi = 0; mi < 8; ++mi) {
#pragma unroll
    for (int r = 0; r < 4; ++r) {
      const int b = m0 + wm * 128 + mi * 16 + qlane * 4 + r;
      const int idx = b * 1024 + unit;
      const float gi = acc[mi][0][r] + bi;
      const float go = acc[mi][1][r] + bo;
      const float gf = acc[mi][2][r] + bfg;
      const float gz = acc[mi][3][r] + bz + bf2f(Dgz[idx]);
      const float iv = sigmoid_f(gi);
      const float ov = sigmoid_f(go);
      const float fv = sigmoid_f(gf);
      const float zv = tanh_f(gz);
      const float cn = iv * zv + fv * cold[idx];
      const float hn = ov * tanh_f(cn);
      hnew[idx] = hn;
      hnewb[idx] = f2bf(hn);
    }
  }
}

// Dgz[b,u] = sum_k h_hi*W_lo + h_lo*W_hi. M=16384, N=1024, K=2048, NT=32.
__global__ __launch_bounds__(512, 2) void gemm_zcorr2(const unsigned short* __restrict__ Xb,
                                                      const unsigned short* __restrict__ Hlo,
                                                      const unsigned short* __restrict__ Wz2,
                                                      unsigned short* __restrict__ Dgz) {
  __shared__ unsigned short lds[2][2][16384];
  const int tid = threadIdx.x;
  const int lane = tid & 63, wave = tid >> 6;
  const int wm = wave & 1, wn = wave >> 1;
  const int ln = lane & 15, qlane = lane >> 4;
  const int n0 = blockIdx.x << 8, m0 = blockIdx.y << 8;
  const int sr = tid >> 3;
  const int j = ((tid & 7) - (sr & 7)) & 7;

  const unsigned short* gAX[2][2];
  const unsigned short* gAH[2][2];
  const unsigned short* gB[2][2];
#pragma unroll
  for (int hh = 0; hh < 2; ++hh)
#pragma unroll
    for (int u = 0; u < 2; ++u) {
      const int row = hh * 128 + u * 64 + sr;
      gAX[hh][u] = Xb  + (size_t)(m0 + row) * 1536 + 512 + j * 8;
      gAH[hh][u] = Hlo + (size_t)(m0 + row) * 1024 + j * 8;
      gB[hh][u]  = Wz2 + (size_t)(n0 + row) * 2048 + j * 8;
    }
  unsigned short* const dA0 = &lds[0][0][0] + (tid & ~63) * 8;
  unsigned short* const dB0 = &lds[0][1][0] + (tid & ~63) * 8;
  unsigned short* const dA1 = &lds[1][0][0] + (tid & ~63) * 8;
  unsigned short* const dB1 = &lds[1][1][0] + (tid & ~63) * 8;
  const unsigned short* const lA0 = &lds[0][0][0];
  const unsigned short* const lB0 = &lds[0][1][0];
  const unsigned short* const lA1 = &lds[1][0][0];
  const unsigned short* const lB1 = &lds[1][1][0];
  const int sl0 = ((qlane + ln) & 7) * 8;
  const int sl1 = sl0 ^ 32;
  const int aoff0 = (wm * 128 + ln) * 64 + sl0;
  const int aoff1 = (wm * 128 + ln) * 64 + sl1;
  const int boff0 = (wn * 64 + ln) * 64 + sl0;
  const int boff1 = (wn * 64 + ln) * 64 + sl1;

  f32x4 acc[8][4] = {};
  s16x8 aC[4], aN[4], bqA[8], bqB[8];

  ZST_A2(0, dA0); ST_B2(0, dB0);
  ZST_A2(1, dA1); ST_B2(1, dB1);
  VM8;
  BARR;
  BH(bqA, lB0, 0); BH(bqA, lB0, 1);
  AQ(aC, lA0, 0);

  KT_STD(lA0, lA1, lB1, bqA, bqB, NOST, ST_B2(2, dB0), VM4, VM4);  // tile 0
#pragma unroll 1
  for (int t = 1; t < 29; t += 2) {
    KT_STD(lA1, lA0, lB0, bqB, bqA, ZST_A2(t + 1, dA0), ST_B2(t + 2, dB1), VM8, VM4);
    KT_STD(lA0, lA1, lB1, bqA, bqB, ZST_A2(t + 2, dA1), ST_B2(t + 3, dB0), VM8, VM4);
  }
  KT_STD(lA1, lA0, lB0, bqB, bqA, ZST_A2(30, dA0), ST_B2(31, dB1), VM8, VM4);  // tile 29
  KT_STD(lA0, lA1, lB1, bqA, bqB, ZST_A2(31, dA1), NOST, VM4, VM0);            // tile 30
  KT_LAST(lA1, bqB);                                                           // tile 31

#pragma unroll
  for (int mi = 0; mi < 8; ++mi) {
#pragma unroll
    for (int r = 0; r < 4; ++r) {
      const int b = m0 + wm * 128 + mi * 16 + qlane * 4 + r;
#pragma unroll
      for (int ni = 0; ni < 4; ++ni) {
        const int n = n0 + wn * 64 + ni * 16 + ln;
        Dgz[b * 1024 + n] = f2bf(acc[mi][ni][r]);
      }
    }
  }
}

// out = h_new @ Wout^T + bout. M=16384, N=512, K=1024.
__global__ __launch_bounds__(256) void gemm_out(const unsigned short* __restrict__ Hb,
                                                const unsigned short* __restrict__ Wo,
                                                const float* __restrict__ bout,
                                                float* __restrict__ out) {
  __shared__ unsigned short As[8192];
  __shared__ unsigned short Bs[8192];
  const int n0 = blockIdx.x * 128;
  const int m0 = blockIdx.y * 128;
  const int tid = threadIdx.x, lane = tid & 63, wave = tid >> 6;
  const unsigned short *ga[4], *gb[4];
  unsigned short *la[4], *lb[4];
#pragma unroll
  for (int u = 0; u < 4; ++u) {
    int p = u * 256 + tid;
    int r = p >> 3;
    int jj = ((p & 7) - r) & 7;
    ga[u] = Hb + (size_t)(m0 + r) * 1024 + jj * 8;
    gb[u] = Wo + (size_t)(n0 + r) * 1024 + jj * 8;
    la[u] = As + (u * 256 + (tid & ~63)) * 8;
    lb[u] = Bs + (u * 256 + (tid & ~63)) * 8;
  }
  f32x4 acc[4][4] = {};
  for (int kk = 0; kk < 16; ++kk) {
#pragma unroll
    for (int u = 0; u < 4; ++u) { stage16(ga[u], la[u]); stage16(gb[u], lb[u]); }
#pragma unroll
    for (int u = 0; u < 4; ++u) { ga[u] += 64; gb[u] += 64; }
    __syncthreads();
    mma_step64(As, Bs, acc, lane, wave);
    __syncthreads();
  }
  const int wm = wave & 1, wn = wave >> 1;
  const int ln = lane & 15, q = lane >> 4;
  float bo_[4];
#pragma unroll
  for (int ni = 0; ni < 4; ++ni) bo_[ni] = bout[n0 + wn * 64 + ni * 16 + ln];
#pragma unroll
  for (int mi = 0; mi < 4; ++mi) {
#pragma unroll
    for (int r = 0; r < 4; ++r) {
      const int b = m0 + wm * 64 + mi * 16 + q * 4 + r;
#pragma unroll
      for (int ni = 0; ni < 4; ++ni) {
        const int n = n0 + wn * 64 + ni * 16 + ln;
        out[b * 512 + n] = acc[mi][ni][r] + bo_[ni];
      }
    }
  }
}

extern "C" void kernel_launch(void* const* d_in, const int* in_sizes, int n_in,
                              void* d_out, int out_size, void* d_ws, size_t ws_size,
                              hipStream_t stream) {
  const float* inp  = (const float*)d_in[0];
  const float* h    = (const float*)d_in[1];
  const float* c    = (const float*)d_in[2];
  const float* Wx   = (const float*)d_in[3];
  const float* bx   = (const float*)d_in[4];
  const float* Wh   = (const float*)d_in[5];
  const float* Wout = (const float*)d_in[6];
  const float* bout = (const float*)d_in[7];

  float* out  = (float*)d_out;                       // [B, 512]
  float* hnew = out + (size_t)BB * OO;               // [B, 1024]

  char* ws = (char*)d_ws;
  unsigned short* Xb  = (unsigned short*)(ws);                  //  50,331,648 B
  unsigned short* Wg  = (unsigned short*)(ws + 50331648);       //  12,582,912 B
  unsigned short* Wo  = (unsigned short*)(ws + 62914560);       //   1,048,576 B
  unsigned short* Hb  = (unsigned short*)(ws + 63963136);       //  33,554,432 B
  unsigned short* Hlo = (unsigned short*)(ws + 97517568);       //  33,554,432 B
  unsigned short* Wz2 = (unsigned short*)(ws + 131072000);      //   4,194,304 B
  unsigned short* Dgz = (unsigned short*)(ws + 135266304);      //  33,554,432 B

  prep_X   <<<12288, 256, 0, stream>>>(inp, h, Xb, Hlo);
  prep_Wg  <<<3072,  256, 0, stream>>>(Wx, Wh, Wg);
  prep_Wz2 <<<1024,  256, 0, stream>>>(Wh + 3 * 1024 * 1024, Wz2);
  prep_Wout<<<256,   256, 0, stream>>>(Wout, Wo);
  gemm_zcorr2<<<dim3(4, 64),  512, 0, stream>>>(Xb, Hlo, Wz2, Dgz);
  gemm_gates2<<<dim3(16, 64), 512, 0, stream>>>(Xb, Wg, bx, c, Dgz, hnew, Hb);
  gemm_out  <<<dim3(4, 128),  256, 0, stream>>>(Hb, Wo, bout, out);
}

// Round 4
// 558.609 us; speedup vs baseline: 1.2840x; 1.2840x over previous
//
#include <hip/hip_runtime.h>
#include <stdint.h>

// Problem constants
#define BB 16384
#define II 512
#define HH 1024
#define OO 512

typedef short s16x8 __attribute__((ext_vector_type(8)));
typedef float f32x4 __attribute__((ext_vector_type(4)));

__device__ __forceinline__ unsigned short f2bf(float x) {
  union { float f; unsigned u; } v; v.f = x;
  return (unsigned short)((v.u + 0x7fffu + ((v.u >> 16) & 1u)) >> 16);  // RNE
}
__device__ __forceinline__ float bf2f(unsigned short b) {
  union { unsigned u; float f; } v; v.u = ((unsigned)b) << 16;
  return v.f;
}
__device__ __forceinline__ float sigmoid_f(float x) {
  return 1.0f / (1.0f + __expf(-x));
}
__device__ __forceinline__ float tanh_f(float x) {
  float ax = fabsf(x);
  float e = __expf(-2.0f * ax);
  float t = (1.0f - e) / (1.0f + e);
  return x >= 0.0f ? t : -t;
}

// async global->LDS, 16B per lane, LDS dest = wave-uniform base + lane*16
__device__ __forceinline__ void stage16(const void* g, void* l) {
  __builtin_amdgcn_global_load_lds((const __attribute__((address_space(1))) void*)g,
                                   (__attribute__((address_space(3))) void*)l,
                                   16, 0, 0);
}

// ---- 128-tile helper (kept for gemm_out) ----
__device__ __forceinline__ void mma_step64(const unsigned short* As, const unsigned short* Bs,
                                           f32x4 acc[4][4], int lane, int wave) {
  const int wm = wave & 1, wn = wave >> 1;
  const int ln = lane & 15, q = lane >> 4;
#pragma unroll
  for (int s = 0; s < 2; ++s) {
    s16x8 af[4], bfr[4];
#pragma unroll
    for (int i = 0; i < 4; ++i) {
      const int r = wm * 64 + i * 16 + ln;
      af[i] = *(const s16x8*)(As + r * 64 + ((((s << 2) + q) + r) & 7) * 8);
    }
#pragma unroll
    for (int i = 0; i < 4; ++i) {
      const int r = wn * 64 + i * 16 + ln;
      bfr[i] = *(const s16x8*)(Bs + r * 64 + ((((s << 2) + q) + r) & 7) * 8);
    }
#pragma unroll
    for (int mi = 0; mi < 4; ++mi)
#pragma unroll
      for (int ni = 0; ni < 4; ++ni)
        acc[mi][ni] = __builtin_amdgcn_mfma_f32_16x16x32_bf16(af[mi], bfr[ni], acc[mi][ni], 0, 0, 0);
  }
}

// ---------------- prep kernels ----------------

__global__ __launch_bounds__(256) void prep_X(const float* __restrict__ inp,
                                              const float* __restrict__ h,
                                              unsigned short* __restrict__ Xb,
                                              unsigned short* __restrict__ Hlo) {
  int t = blockIdx.x * 256 + threadIdx.x;
  int base = t * 8;
  int b = base / 1536;
  int k = base - b * 1536;
  const float* src = (k < 512) ? (inp + b * 512 + k) : (h + b * 1024 + (k - 512));
  float4 v0 = *(const float4*)src;
  float4 v1 = *(const float4*)(src + 4);
  float f[8] = {v0.x, v0.y, v0.z, v0.w, v1.x, v1.y, v1.z, v1.w};
  unsigned short hi[8];
#pragma unroll
  for (int i = 0; i < 8; ++i) hi[i] = f2bf(f[i]);
  *(s16x8*)(Xb + base) = *(s16x8*)hi;
  if (k >= 512) {
    unsigned short lo[8];
#pragma unroll
    for (int i = 0; i < 8; ++i) lo[i] = f2bf(f[i] - bf2f(hi[i]));
    *(s16x8*)(Hlo + b * 1024 + (k - 512)) = *(s16x8*)lo;
  }
}

// Gate weights -> bf16 [4096][1536], K-contiguous, columns permuted for BN=256:
// n = blkX*256 + wn*64 + gate*16 + ln  <->  unit = blkX*64 + wn*16 + ln
__global__ __launch_bounds__(256) void prep_Wg(const float* __restrict__ Wx,
                                               const float* __restrict__ Wh,
                                               unsigned short* __restrict__ Wg) {
  int t = blockIdx.x * 256 + threadIdx.x;
  int base = t * 8;
  int n = base / 1536;
  int k = base - n * 1536;
  int r = n & 255;
  int gate = (r >> 4) & 3;
  int unit = ((n >> 8) << 6) + (((r >> 6) & 3) << 4) + (r & 15);
  const float* src = (k < 512) ? (Wx + (gate * 1024 + unit) * 512 + k)
                               : (Wh + (gate * 1024 + unit) * 1024 + (k - 512));
  float4 v0 = *(const float4*)src;
  float4 v1 = *(const float4*)(src + 4);
  float f[8] = {v0.x, v0.y, v0.z, v0.w, v1.x, v1.y, v1.z, v1.w};
  unsigned short o[8];
#pragma unroll
  for (int i = 0; i < 8; ++i) o[i] = f2bf(f[i]);
  *(s16x8*)(Wg + base) = *(s16x8*)o;
}

// z-correction weights [1024][2048]: k<1024 -> W_lo(Whz), k>=1024 -> W_hi(Whz)
__global__ __launch_bounds__(256) void prep_Wz2(const float* __restrict__ Whz,
                                                unsigned short* __restrict__ Wz2) {
  int t = blockIdx.x * 256 + threadIdx.x;
  int base = t * 8;
  int n = base >> 11;
  int k = base & 2047;
  int klo = (k < 1024) ? k : (k - 1024);
  const float* src = Whz + n * 1024 + klo;
  float4 v0 = *(const float4*)src;
  float4 v1 = *(const float4*)(src + 4);
  float f[8] = {v0.x, v0.y, v0.z, v0.w, v1.x, v1.y, v1.z, v1.w};
  unsigned short o[8];
  if (k < 1024) {
#pragma unroll
    for (int i = 0; i < 8; ++i) { unsigned short h_ = f2bf(f[i]); o[i] = f2bf(f[i] - bf2f(h_)); }
  } else {
#pragma unroll
    for (int i = 0; i < 8; ++i) o[i] = f2bf(f[i]);
  }
  *(s16x8*)(Wz2 + base) = *(s16x8*)o;
}

__global__ __launch_bounds__(256) void prep_Wout(const float* __restrict__ Wout,
                                                 unsigned short* __restrict__ Wo) {
  int t = blockIdx.x * 256 + threadIdx.x;
  int base = t * 8;
  float4 v0 = *(const float4*)(Wout + base);
  float4 v1 = *(const float4*)(Wout + base + 4);
  float f[8] = {v0.x, v0.y, v0.z, v0.w, v1.x, v1.y, v1.z, v1.w};
  unsigned short o[8];
#pragma unroll
  for (int i = 0; i < 8; ++i) o[i] = f2bf(f[i]);
  *(s16x8*)(Wo + base) = *(s16x8*)o;
}

// ========= 256x256 / 8-wave GEMM, m201-style balanced 4-phase schedule =========
//
// LDS: lds[buf][A/B][256*64 bf16]; chunk-rotation swizzle (slot=(j+row)&7),
// conflict-free (measured 0 across rounds). 1 block/CU, 2 waves/SIMD.
//
// Read distribution 12/4/4/4 (vs round-1's 16/8/0/0): each phase's 4 A-reads are
// issued IMMEDIATELY AFTER the previous phase's 16 MFMAs in program order.
// s_barrier does NOT drain the MFMA pipe, so those reads execute on the LDS pipe
// while the MFMA pipe drains the previous phase -> both pipes stay fed. Each
// lgkm(0) then waits on reads covered by [MFMA-issue tail + barrier stagger].
// A-frag registers alternate aE/aO (two 4-reg sets); B held in bq[8] for the
// tile. Register budget = round 1's (no spill): acc 128 (AGPR) + bq 32 + aE/aO
// 32 + addresses ~= 124 arch VGPRs.
//
// Tile t (cur=t&1, reads dA[cur]/dB[cur]); stage 2 loads/phase:
//  ph0: read B[8]+A q0->aE; stage A(t+1)h0 -> dA[cur^1];  bar; lgkm0; MFMA q0
//  ph1: read A q1->aO;      stage A(t+1)h1 -> dA[cur^1];  bar; lgkm0; MFMA q1
//  ph2: read A q2->aE;      stage B(t+2)h0 -> dB[cur];    bar; lgkm0; MFMA q2
//  ph3: read A q3->aO;      stage B(t+2)h1 -> dB[cur];    bar; lgkm0; MFMA q3
//  end: vmcnt(4); bar
// Hazard audit (single barrier per phase):
//  - B(t+2)->dB[cur] at ph2: every wave's B reads (ph0) are drained by its own
//    ph0 lgkm0, which precedes ph1's barrier; any wave executing ph2 code has
//    passed ph1's barrier => all waves' B reads complete. Safe.
//  - A(t+1)->dA[cur^1] at ph0: that buffer's last reads were tile t-1 ph3,
//    drained by each wave's ph3 lgkm0 before the tile-end barrier. Safe.
//  - vmcnt(4) at t-end: outstanding = B(t+1)[4, staged t-1 ph2/3] + A(t+1)[4,
//    t ph0/1] + B(t+2)[4, t ph2/3]; allowing 4 => A(t+1),B(t+1) certified,
//    B(t+2) stays in flight. Waits only on loads >= 2 phases old.
//  - Max wave drift = 1 barrier; all staging writes sit behind the barrier that
//    certifies the readers they could collide with.

#define RD_A(CA, MI, KS) (*(const s16x8*)((CA) + ((KS) ? aoff1 : aoff0) + (MI) * 1024))
#define RD_B(CB, NI, KS) (*(const s16x8*)((CB) + ((KS) ? boff1 : boff0) + (NI) * 1024))
#define VM8 asm volatile("s_waitcnt vmcnt(8)" ::: "memory")
#define VM4 asm volatile("s_waitcnt vmcnt(4)" ::: "memory")
#define VM0 asm volatile("s_waitcnt vmcnt(0)" ::: "memory")
#define LGKM0 asm volatile("s_waitcnt lgkmcnt(0)" ::: "memory")
#define SB0 __builtin_amdgcn_sched_barrier(0)
#define BARR __builtin_amdgcn_s_barrier()
#define VMNONE ((void)0)
#define NOST ((void)0)

// read one A quadrant (rows wm*128 + [2Q*16, 2Q*16+32)), both k-slices
#define AQ(S, CA, Q) do { \
  S[0] = RD_A(CA, 2 * (Q), 0);  S[1] = RD_A(CA, 2 * (Q) + 1, 0); \
  S[2] = RD_A(CA, 2 * (Q), 1);  S[3] = RD_A(CA, 2 * (Q) + 1, 1); } while (0)
// read one B k-slice into bq[4*KS..4*KS+3]
#define BH(BQ, CB, KS) do { \
  BQ[4 * (KS) + 0] = RD_B(CB, 0, KS); BQ[4 * (KS) + 1] = RD_B(CB, 1, KS); \
  BQ[4 * (KS) + 2] = RD_B(CB, 2, KS); BQ[4 * (KS) + 3] = RD_B(CB, 3, KS); } while (0)

// half-tile stages (2 x stage16 each)
#define SA_H0(TT, DB) do { \
  stage16(gA[0][0] + (size_t)(TT) * 64, (DB)); \
  stage16(gA[0][1] + (size_t)(TT) * 64, (DB) + 4096); } while (0)
#define SA_H1(TT, DB) do { \
  stage16(gA[1][0] + (size_t)(TT) * 64, (DB) + 8192); \
  stage16(gA[1][1] + (size_t)(TT) * 64, (DB) + 12288); } while (0)
#define SB_H0(TT, DB) do { \
  stage16(gB[0][0] + (size_t)(TT) * 64, (DB)); \
  stage16(gB[0][1] + (size_t)(TT) * 64, (DB) + 4096); } while (0)
#define SB_H1(TT, DB) do { \
  stage16(gB[1][0] + (size_t)(TT) * 64, (DB) + 8192); \
  stage16(gB[1][1] + (size_t)(TT) * 64, (DB) + 12288); } while (0)
// zcorr A source switches at tile 16 (h_hi from Xb, then h_lo from Hlo)
#define ZSA_H0(TT, DB) do { \
  const unsigned short *z0_, *z1_; \
  if ((TT) < 16) { z0_ = gAX[0][0] + (size_t)(TT) * 64; z1_ = gAX[0][1] + (size_t)(TT) * 64; } \
  else { z0_ = gAH[0][0] + (size_t)((TT) - 16) * 64; z1_ = gAH[0][1] + (size_t)((TT) - 16) * 64; } \
  stage16(z0_, (DB)); stage16(z1_, (DB) + 4096); } while (0)
#define ZSA_H1(TT, DB) do { \
  const unsigned short *z2_, *z3_; \
  if ((TT) < 16) { z2_ = gAX[1][0] + (size_t)(TT) * 64; z3_ = gAX[1][1] + (size_t)(TT) * 64; } \
  else { z2_ = gAH[1][0] + (size_t)((TT) - 16) * 64; z3_ = gAH[1][1] + (size_t)((TT) - 16) * 64; } \
  stage16(z2_, (DB) + 8192); stage16(z3_, (DB) + 12288); } while (0)

// 16 MFMA for output quadrant Q (acc rows 2Q, 2Q+1)
#define MFMAQ(Q, S) do { \
  __builtin_amdgcn_s_setprio(1); \
  _Pragma("unroll") \
  for (int ni = 0; ni < 4; ++ni) { \
    acc[2 * (Q)    ][ni] = __builtin_amdgcn_mfma_f32_16x16x32_bf16(S[0], bq[ni], acc[2 * (Q)    ][ni], 0, 0, 0); \
    acc[2 * (Q) + 1][ni] = __builtin_amdgcn_mfma_f32_16x16x32_bf16(S[1], bq[ni], acc[2 * (Q) + 1][ni], 0, 0, 0); \
  } \
  _Pragma("unroll") \
  for (int ni = 0; ni < 4; ++ni) { \
    acc[2 * (Q)    ][ni] = __builtin_amdgcn_mfma_f32_16x16x32_bf16(S[2], bq[4 + ni], acc[2 * (Q)    ][ni], 0, 0, 0); \
    acc[2 * (Q) + 1][ni] = __builtin_amdgcn_mfma_f32_16x16x32_bf16(S[3], bq[4 + ni], acc[2 * (Q) + 1][ni], 0, 0, 0); \
  } \
  __builtin_amdgcn_s_setprio(0); \
} while (0)

#define KTILE(CA, CB, S0, S1, S2, S3, VMX) do { \
  s16x8 bq[8], aE[4], aO[4]; \
  BH(bq, CB, 0); BH(bq, CB, 1); \
  AQ(aE, CA, 0); \
  S0; \
  BARR; LGKM0; SB0; \
  MFMAQ(0, aE); \
  AQ(aO, CA, 1); S1; \
  BARR; LGKM0; SB0; \
  MFMAQ(1, aO); \
  AQ(aE, CA, 2); S2; \
  BARR; LGKM0; SB0; \
  MFMAQ(2, aE); \
  AQ(aO, CA, 3); S3; \
  BARR; LGKM0; SB0; \
  MFMAQ(3, aO); \
  VMX; BARR; \
} while (0)

// Gate GEMM + fused LSTM epilogue. M=16384, N=4096 (permuted), K=1536, NT=24.
__global__ __launch_bounds__(512, 2) void gemm_gates2(const unsigned short* __restrict__ Xb,
                                                      const unsigned short* __restrict__ Wg,
                                                      const float* __restrict__ bx,
                                                      const float* __restrict__ cold,
                                                      const unsigned short* __restrict__ Dgz,
                                                      float* __restrict__ hnew,
                                                      unsigned short* __restrict__ hnewb) {
  __shared__ unsigned short lds[2][2][16384];   // 128 KiB
  const int tid = threadIdx.x;
  const int lane = tid & 63, wave = tid >> 6;
  const int wm = wave & 1, wn = wave >> 1;
  const int ln = lane & 15, qlane = lane >> 4;
  // natural mapping: bx mod 8 pins each XCD to 2 B-panels (L2-resident)
  const int n0 = blockIdx.x << 8, m0 = blockIdx.y << 8;
  const int sr = tid >> 3;
  const int j = ((tid & 7) - (sr & 7)) & 7;

  const unsigned short* gA[2][2];
  const unsigned short* gB[2][2];
#pragma unroll
  for (int hh = 0; hh < 2; ++hh)
#pragma unroll
    for (int u = 0; u < 2; ++u) {
      const int row = hh * 128 + u * 64 + sr;
      gA[hh][u] = Xb + (size_t)(m0 + row) * 1536 + j * 8;
      gB[hh][u] = Wg + (size_t)(n0 + row) * 1536 + j * 8;
    }
  unsigned short* const dA0 = &lds[0][0][0] + (tid & ~63) * 8;
  unsigned short* const dB0 = &lds[0][1][0] + (tid & ~63) * 8;
  unsigned short* const dA1 = &lds[1][0][0] + (tid & ~63) * 8;
  unsigned short* const dB1 = &lds[1][1][0] + (tid & ~63) * 8;
  const unsigned short* const lA0 = &lds[0][0][0];
  const unsigned short* const lB0 = &lds[0][1][0];
  const unsigned short* const lA1 = &lds[1][0][0];
  const unsigned short* const lB1 = &lds[1][1][0];
  const int sl0 = ((qlane + ln) & 7) * 8;
  const int sl1 = sl0 ^ 32;
  const int aoff0 = (wm * 128 + ln) * 64 + sl0;
  const int aoff1 = (wm * 128 + ln) * 64 + sl1;
  const int boff0 = (wn * 64 + ln) * 64 + sl0;
  const int boff1 = (wn * 64 + ln) * 64 + sl1;

  f32x4 acc[8][4] = {};

  // prologue: stage tiles 0 and 1 (16 loads); wait for tile 0's 8
  SA_H0(0, dA0); SA_H1(0, dA0); SB_H0(0, dB0); SB_H1(0, dB0);
  SA_H0(1, dA1); SA_H1(1, dA1); SB_H0(1, dB1); SB_H1(1, dB1);
  VM8;
  BARR;

  // tile 0: A(1),B(1) already staged; stage only B(2). End vmcnt(4) drains the
  // prologue's tile-1 loads (8), leaves B(2)'s 4 in flight.
  KTILE(lA0, lB0, NOST, NOST, SB_H0(2, dB0), SB_H1(2, dB0), VM4);
#pragma unroll 1
  for (int t = 1; t < 21; t += 2) {
    KTILE(lA1, lB1, SA_H0(t + 1, dA0), SA_H1(t + 1, dA0),
                    SB_H0(t + 2, dB1), SB_H1(t + 2, dB1), VM4);
    KTILE(lA0, lB0, SA_H0(t + 2, dA1), SA_H1(t + 2, dA1),
                    SB_H0(t + 3, dB0), SB_H1(t + 3, dB0), VM4);
  }
  KTILE(lA1, lB1, SA_H0(22, dA0), SA_H1(22, dA0),
                  SB_H0(23, dB1), SB_H1(23, dB1), VM4);             // tile 21
  KTILE(lA0, lB0, SA_H0(23, dA1), SA_H1(23, dA1), NOST, NOST, VM0); // tile 22
  KTILE(lA1, lB1, NOST, NOST, NOST, NOST, VMNONE);                  // tile 23

  // Epilogue: acc[mi][ni] is gate ni for unit = blkX*64 + wn*16 + ln.
  const int unit = ((int)blockIdx.x << 6) + (wn << 4) + ln;
  const float bi = bx[unit];
  const float bo = bx[1024 + unit];
  const float bfg = bx[2048 + unit];
  const float bz = bx[3072 + unit];
#pragma unroll
  for (int mi = 0; mi < 8; ++mi) {
#pragma unroll
    for (int r = 0; r < 4; ++r) {
      const int b = m0 + wm * 128 + mi * 16 + qlane * 4 + r;
      const int idx = b * 1024 + unit;
      const float gi = acc[mi][0][r] + bi;
      const float go = acc[mi][1][r] + bo;
      const float gf = acc[mi][2][r] + bfg;
      const float gz = acc[mi][3][r] + bz + bf2f(Dgz[idx]);
      const float iv = sigmoid_f(gi);
      const float ov = sigmoid_f(go);
      const float fv = sigmoid_f(gf);
      const float zv = tanh_f(gz);
      const float cn = iv * zv + fv * cold[idx];
      const float hn = ov * tanh_f(cn);
      hnew[idx] = hn;
      hnewb[idx] = f2bf(hn);
    }
  }
}

// Dgz[b,u] = sum_k h_hi*W_lo + h_lo*W_hi. M=16384, N=1024, K=2048, NT=32.
__global__ __launch_bounds__(512, 2) void gemm_zcorr2(const unsigned short* __restrict__ Xb,
                                                      const unsigned short* __restrict__ Hlo,
                                                      const unsigned short* __restrict__ Wz2,
                                                      unsigned short* __restrict__ Dgz) {
  __shared__ unsigned short lds[2][2][16384];
  const int tid = threadIdx.x;
  const int lane = tid & 63, wave = tid >> 6;
  const int wm = wave & 1, wn = wave >> 1;
  const int ln = lane & 15, qlane = lane >> 4;
  const int n0 = blockIdx.x << 8, m0 = blockIdx.y << 8;
  const int sr = tid >> 3;
  const int j = ((tid & 7) - (sr & 7)) & 7;

  const unsigned short* gAX[2][2];
  const unsigned short* gAH[2][2];
  const unsigned short* gB[2][2];
#pragma unroll
  for (int hh = 0; hh < 2; ++hh)
#pragma unroll
    for (int u = 0; u < 2; ++u) {
      const int row = hh * 128 + u * 64 + sr;
      gAX[hh][u] = Xb  + (size_t)(m0 + row) * 1536 + 512 + j * 8;
      gAH[hh][u] = Hlo + (size_t)(m0 + row) * 1024 + j * 8;
      gB[hh][u]  = Wz2 + (size_t)(n0 + row) * 2048 + j * 8;
    }
  unsigned short* const dA0 = &lds[0][0][0] + (tid & ~63) * 8;
  unsigned short* const dB0 = &lds[0][1][0] + (tid & ~63) * 8;
  unsigned short* const dA1 = &lds[1][0][0] + (tid & ~63) * 8;
  unsigned short* const dB1 = &lds[1][1][0] + (tid & ~63) * 8;
  const unsigned short* const lA0 = &lds[0][0][0];
  const unsigned short* const lB0 = &lds[0][1][0];
  const unsigned short* const lA1 = &lds[1][0][0];
  const unsigned short* const lB1 = &lds[1][1][0];
  const int sl0 = ((qlane + ln) & 7) * 8;
  const int sl1 = sl0 ^ 32;
  const int aoff0 = (wm * 128 + ln) * 64 + sl0;
  const int aoff1 = (wm * 128 + ln) * 64 + sl1;
  const int boff0 = (wn * 64 + ln) * 64 + sl0;
  const int boff1 = (wn * 64 + ln) * 64 + sl1;

  f32x4 acc[8][4] = {};

  ZSA_H0(0, dA0); ZSA_H1(0, dA0); SB_H0(0, dB0); SB_H1(0, dB0);
  ZSA_H0(1, dA1); ZSA_H1(1, dA1); SB_H0(1, dB1); SB_H1(1, dB1);
  VM8;
  BARR;

  KTILE(lA0, lB0, NOST, NOST, SB_H0(2, dB0), SB_H1(2, dB0), VM4);   // tile 0
#pragma unroll 1
  for (int t = 1; t < 29; t += 2) {
    KTILE(lA1, lB1, ZSA_H0(t + 1, dA0), ZSA_H1(t + 1, dA0),
                    SB_H0(t + 2, dB1), SB_H1(t + 2, dB1), VM4);
    KTILE(lA0, lB0, ZSA_H0(t + 2, dA1), ZSA_H1(t + 2, dA1),
                    SB_H0(t + 3, dB0), SB_H1(t + 3, dB0), VM4);
  }
  KTILE(lA1, lB1, ZSA_H0(30, dA0), ZSA_H1(30, dA0),
                  SB_H0(31, dB1), SB_H1(31, dB1), VM4);               // tile 29
  KTILE(lA0, lB0, ZSA_H0(31, dA1), ZSA_H1(31, dA1), NOST, NOST, VM0); // tile 30
  KTILE(lA1, lB1, NOST, NOST, NOST, NOST, VMNONE);                    // tile 31

#pragma unroll
  for (int mi = 0; mi < 8; ++mi) {
#pragma unroll
    for (int r = 0; r < 4; ++r) {
      const int b = m0 + wm * 128 + mi * 16 + qlane * 4 + r;
#pragma unroll
      for (int ni = 0; ni < 4; ++ni) {
        const int n = n0 + wn * 64 + ni * 16 + ln;
        Dgz[b * 1024 + n] = f2bf(acc[mi][ni][r]);
      }
    }
  }
}

// out = h_new @ Wout^T + bout. M=16384, N=512, K=1024.
__global__ __launch_bounds__(256) void gemm_out(const unsigned short* __restrict__ Hb,
                                                const unsigned short* __restrict__ Wo,
                                                const float* __restrict__ bout,
                                                float* __restrict__ out) {
  __shared__ unsigned short As[8192];
  __shared__ unsigned short Bs[8192];
  const int n0 = blockIdx.x * 128;
  const int m0 = blockIdx.y * 128;
  const int tid = threadIdx.x, lane = tid & 63, wave = tid >> 6;
  const unsigned short *ga[4], *gb[4];
  unsigned short *la[4], *lb[4];
#pragma unroll
  for (int u = 0; u < 4; ++u) {
    int p = u * 256 + tid;
    int r = p >> 3;
    int jj = ((p & 7) - r) & 7;
    ga[u] = Hb + (size_t)(m0 + r) * 1024 + jj * 8;
    gb[u] = Wo + (size_t)(n0 + r) * 1024 + jj * 8;
    la[u] = As + (u * 256 + (tid & ~63)) * 8;
    lb[u] = Bs + (u * 256 + (tid & ~63)) * 8;
  }
  f32x4 acc[4][4] = {};
  for (int kk = 0; kk < 16; ++kk) {
#pragma unroll
    for (int u = 0; u < 4; ++u) { stage16(ga[u], la[u]); stage16(gb[u], lb[u]); }
#pragma unroll
    for (int u = 0; u < 4; ++u) { ga[u] += 64; gb[u] += 64; }
    __syncthreads();
    mma_step64(As, Bs, acc, lane, wave);
    __syncthreads();
  }
  const int wm = wave & 1, wn = wave >> 1;
  const int ln = lane & 15, q = lane >> 4;
  float bo_[4];
#pragma unroll
  for (int ni = 0; ni < 4; ++ni) bo_[ni] = bout[n0 + wn * 64 + ni * 16 + ln];
#pragma unroll
  for (int mi = 0; mi < 4; ++mi) {
#pragma unroll
    for (int r = 0; r < 4; ++r) {
      const int b = m0 + wm * 64 + mi * 16 + q * 4 + r;
#pragma unroll
      for (int ni = 0; ni < 4; ++ni) {
        const int n = n0 + wn * 64 + ni * 16 + ln;
        out[b * 512 + n] = acc[mi][ni][r] + bo_[ni];
      }
    }
  }
}

extern "C" void kernel_launch(void* const* d_in, const int* in_sizes, int n_in,
                              void* d_out, int out_size, void* d_ws, size_t ws_size,
                              hipStream_t stream) {
  const float* inp  = (const float*)d_in[0];
  const float* h    = (const float*)d_in[1];
  const float* c    = (const float*)d_in[2];
  const float* Wx   = (const float*)d_in[3];
  const float* bx   = (const float*)d_in[4];
  const float* Wh   = (const float*)d_in[5];
  const float* Wout = (const float*)d_in[6];
  const float* bout = (const float*)d_in[7];

  float* out  = (float*)d_out;                       // [B, 512]
  float* hnew = out + (size_t)BB * OO;               // [B, 1024]

  char* ws = (char*)d_ws;
  unsigned short* Xb  = (unsigned short*)(ws);                  //  50,331,648 B
  unsigned short* Wg  = (unsigned short*)(ws + 50331648);       //  12,582,912 B
  unsigned short* Wo  = (unsigned short*)(ws + 62914560);       //   1,048,576 B
  unsigned short* Hb  = (unsigned short*)(ws + 63963136);       //  33,554,432 B
  unsigned short* Hlo = (unsigned short*)(ws + 97517568);       //  33,554,432 B
  unsigned short* Wz2 = (unsigned short*)(ws + 131072000);      //   4,194,304 B
  unsigned short* Dgz = (unsigned short*)(ws + 135266304);      //  33,554,432 B

  prep_X   <<<12288, 256, 0, stream>>>(inp, h, Xb, Hlo);
  prep_Wg  <<<3072,  256, 0, stream>>>(Wx, Wh, Wg);
  prep_Wz2 <<<1024,  256, 0, stream>>>(Wh + 3 * 1024 * 1024, Wz2);
  prep_Wout<<<256,   256, 0, stream>>>(Wout, Wo);
  gemm_zcorr2<<<dim3(4, 64),  512, 0, stream>>>(Xb, Hlo, Wz2, Dgz);
  gemm_gates2<<<dim3(16, 64), 512, 0, stream>>>(Xb, Wg, bx, c, Dgz, hnew, Hb);
  gemm_out  <<<dim3(4, 128),  256, 0, stream>>>(Hb, Wo, bout, out);
}

// Round 5
// 551.847 us; speedup vs baseline: 1.2997x; 1.0123x over previous
//
#include <hip/hip_runtime.h>
#include <stdint.h>

// Problem constants
#define BB 16384
#define II 512
#define HH 1024
#define OO 512

typedef short s16x8 __attribute__((ext_vector_type(8)));
typedef float f32x4 __attribute__((ext_vector_type(4)));

__device__ __forceinline__ unsigned short f2bf(float x) {
  union { float f; unsigned u; } v; v.f = x;
  return (unsigned short)((v.u + 0x7fffu + ((v.u >> 16) & 1u)) >> 16);  // RNE
}
__device__ __forceinline__ float bf2f(unsigned short b) {
  union { unsigned u; float f; } v; v.u = ((unsigned)b) << 16;
  return v.f;
}
__device__ __forceinline__ float sigmoid_f(float x) {
  return 1.0f / (1.0f + __expf(-x));
}
__device__ __forceinline__ float tanh_f(float x) {
  float ax = fabsf(x);
  float e = __expf(-2.0f * ax);
  float t = (1.0f - e) / (1.0f + e);
  return x >= 0.0f ? t : -t;
}

// async global->LDS, 16B per lane, LDS dest = wave-uniform base + lane*16
__device__ __forceinline__ void stage16(const void* g, void* l) {
  __builtin_amdgcn_global_load_lds((const __attribute__((address_space(1))) void*)g,
                                   (__attribute__((address_space(3))) void*)l,
                                   16, 0, 0);
}

// ---- 128-tile helper (kept for gemm_out) ----
__device__ __forceinline__ void mma_step64(const unsigned short* As, const unsigned short* Bs,
                                           f32x4 acc[4][4], int lane, int wave) {
  const int wm = wave & 1, wn = wave >> 1;
  const int ln = lane & 15, q = lane >> 4;
#pragma unroll
  for (int s = 0; s < 2; ++s) {
    s16x8 af[4], bfr[4];
#pragma unroll
    for (int i = 0; i < 4; ++i) {
      const int r = wm * 64 + i * 16 + ln;
      af[i] = *(const s16x8*)(As + r * 64 + ((((s << 2) + q) + r) & 7) * 8);
    }
#pragma unroll
    for (int i = 0; i < 4; ++i) {
      const int r = wn * 64 + i * 16 + ln;
      bfr[i] = *(const s16x8*)(Bs + r * 64 + ((((s << 2) + q) + r) & 7) * 8);
    }
#pragma unroll
    for (int mi = 0; mi < 4; ++mi)
#pragma unroll
      for (int ni = 0; ni < 4; ++ni)
        acc[mi][ni] = __builtin_amdgcn_mfma_f32_16x16x32_bf16(af[mi], bfr[ni], acc[mi][ni], 0, 0, 0);
  }
}

// ---------------- fused prep kernel (one launch for all 4 preps) ----------------
// bid < 12288           : X/H -> Xb (+ Hlo)
// 12288 <= bid < 15360  : gate weights -> Wg (BN=256 permute)
// 15360 <= bid < 16384  : z-correction weights -> Wz2
// bid >= 16384          : Wout -> Wo
__global__ __launch_bounds__(256) void prep_all(const float* __restrict__ inp,
                                                const float* __restrict__ h,
                                                const float* __restrict__ Wx,
                                                const float* __restrict__ Wh,
                                                const float* __restrict__ Wout,
                                                unsigned short* __restrict__ Xb,
                                                unsigned short* __restrict__ Hlo,
                                                unsigned short* __restrict__ Wg,
                                                unsigned short* __restrict__ Wz2,
                                                unsigned short* __restrict__ Wo) {
  const int bid = blockIdx.x;
  if (bid < 12288) {
    int t = bid * 256 + threadIdx.x;
    int base = t * 8;
    int b = base / 1536;
    int k = base - b * 1536;
    const float* src = (k < 512) ? (inp + b * 512 + k) : (h + b * 1024 + (k - 512));
    float4 v0 = *(const float4*)src;
    float4 v1 = *(const float4*)(src + 4);
    float f[8] = {v0.x, v0.y, v0.z, v0.w, v1.x, v1.y, v1.z, v1.w};
    unsigned short hi[8];
#pragma unroll
    for (int i = 0; i < 8; ++i) hi[i] = f2bf(f[i]);
    *(s16x8*)(Xb + base) = *(s16x8*)hi;
    if (k >= 512) {
      unsigned short lo[8];
#pragma unroll
      for (int i = 0; i < 8; ++i) lo[i] = f2bf(f[i] - bf2f(hi[i]));
      *(s16x8*)(Hlo + b * 1024 + (k - 512)) = *(s16x8*)lo;
    }
  } else if (bid < 15360) {
    // Wg: [4096][1536], columns permuted: n = blkX*256 + wn*64 + gate*16 + ln
    int t = (bid - 12288) * 256 + threadIdx.x;
    int base = t * 8;
    int n = base / 1536;
    int k = base - n * 1536;
    int r = n & 255;
    int gate = (r >> 4) & 3;
    int unit = ((n >> 8) << 6) + (((r >> 6) & 3) << 4) + (r & 15);
    const float* src = (k < 512) ? (Wx + (gate * 1024 + unit) * 512 + k)
                                 : (Wh + (gate * 1024 + unit) * 1024 + (k - 512));
    float4 v0 = *(const float4*)src;
    float4 v1 = *(const float4*)(src + 4);
    float f[8] = {v0.x, v0.y, v0.z, v0.w, v1.x, v1.y, v1.z, v1.w};
    unsigned short o[8];
#pragma unroll
    for (int i = 0; i < 8; ++i) o[i] = f2bf(f[i]);
    *(s16x8*)(Wg + base) = *(s16x8*)o;
  } else if (bid < 16384) {
    // Wz2: [1024][2048]: k<1024 -> W_lo(Whz), k>=1024 -> W_hi(Whz)
    const float* Whz = Wh + 3 * 1024 * 1024;
    int t = (bid - 15360) * 256 + threadIdx.x;
    int base = t * 8;
    int n = base >> 11;
    int k = base & 2047;
    int klo = (k < 1024) ? k : (k - 1024);
    const float* src = Whz + n * 1024 + klo;
    float4 v0 = *(const float4*)src;
    float4 v1 = *(const float4*)(src + 4);
    float f[8] = {v0.x, v0.y, v0.z, v0.w, v1.x, v1.y, v1.z, v1.w};
    unsigned short o[8];
    if (k < 1024) {
#pragma unroll
      for (int i = 0; i < 8; ++i) { unsigned short h_ = f2bf(f[i]); o[i] = f2bf(f[i] - bf2f(h_)); }
    } else {
#pragma unroll
      for (int i = 0; i < 8; ++i) o[i] = f2bf(f[i]);
    }
    *(s16x8*)(Wz2 + base) = *(s16x8*)o;
  } else {
    int t = (bid - 16384) * 256 + threadIdx.x;
    int base = t * 8;
    float4 v0 = *(const float4*)(Wout + base);
    float4 v1 = *(const float4*)(Wout + base + 4);
    float f[8] = {v0.x, v0.y, v0.z, v0.w, v1.x, v1.y, v1.z, v1.w};
    unsigned short o[8];
#pragma unroll
    for (int i = 0; i < 8; ++i) o[i] = f2bf(f[i]);
    *(s16x8*)(Wo + base) = *(s16x8*)o;
  }
}

// ==== 256x256 / 8-wave GEMM, m201-exact phase body (2 barriers/phase) ====
//
// LDS: lds[buf][A/B][256*64 bf16]; chunk-rotation swizzle (slot=(j+row)&7),
// uniform 8-accesses-per-bank per b128 wave-read (0 conflicts measured).
// 1 block/CU (128 KiB LDS + 252 regs/wave), 2 waves/SIMD.
//
// Phase body (m201 template): {ds-reads; stage; [lgkm(8) if 12 reads]; barrier;
// lgkm(0); setprio(1); 16 MFMA; setprio(0); barrier}. Reads balanced 12/4/4/4.
// The trailing barrier keeps waves phase-locked so each phase's read-burst on
// the LDS pipe overlaps the OTHER pipe's drain of the previous MFMA cluster.
// Counted vmcnt(4) once per K-tile; vmcnt(0) only at tile NT-2.
//
// Hazard audit:
//  - S0/S1 (A(t+1) -> dA[other]): that buffer's last reads were tile t-1 ph2/3,
//    drained by their own lgkm(0), >=2 barriers before the write can land. Safe.
//  - S2/S3 (B(t+2) -> dB[cur]): B reads issued ph0, drained by ph0's lgkm(0)
//    before ph0's trailing barrier; stage issued >=3 barriers later. Safe.
//  - vmcnt(4)@tile end: outstanding = B(t+1)[4, oldest] + A(t+1)[4] + B(t+2)[4,
//    newest]; allowing 4 certifies A(t+1),B(t+1) (read next tile), keeps B(t+2)
//    in flight. Barrier after the wait publishes certification to all waves.

#define RD_A(CA, MI, KS) (*(const s16x8*)((CA) + ((KS) ? aoff1 : aoff0) + (MI) * 1024))
#define RD_B(CB, NI, KS) (*(const s16x8*)((CB) + ((KS) ? boff1 : boff0) + (NI) * 1024))
#define VM8 asm volatile("s_waitcnt vmcnt(8)" ::: "memory")
#define VM4 asm volatile("s_waitcnt vmcnt(4)" ::: "memory")
#define VM0 asm volatile("s_waitcnt vmcnt(0)" ::: "memory")
#define LGKM8 asm volatile("s_waitcnt lgkmcnt(8)" ::: "memory")
#define LGKM0 asm volatile("s_waitcnt lgkmcnt(0)" ::: "memory")
#define SB0 __builtin_amdgcn_sched_barrier(0)
#define BARR __builtin_amdgcn_s_barrier()
#define VMNONE ((void)0)
#define NOST ((void)0)

// read one A quadrant (rows wm*128 + [2Q*16, 2Q*16+32)), both k-slices
#define AQ(S, CA, Q) do { \
  S[0] = RD_A(CA, 2 * (Q), 0);  S[1] = RD_A(CA, 2 * (Q) + 1, 0); \
  S[2] = RD_A(CA, 2 * (Q), 1);  S[3] = RD_A(CA, 2 * (Q) + 1, 1); } while (0)
// read one B k-slice into bq[4*KS..4*KS+3]
#define BH(BQ, CB, KS) do { \
  BQ[4 * (KS) + 0] = RD_B(CB, 0, KS); BQ[4 * (KS) + 1] = RD_B(CB, 1, KS); \
  BQ[4 * (KS) + 2] = RD_B(CB, 2, KS); BQ[4 * (KS) + 3] = RD_B(CB, 3, KS); } while (0)

// half-tile stages (2 x stage16 each)
#define SA_H0(TT, DB) do { \
  stage16(gA[0][0] + (size_t)(TT) * 64, (DB)); \
  stage16(gA[0][1] + (size_t)(TT) * 64, (DB) + 4096); } while (0)
#define SA_H1(TT, DB) do { \
  stage16(gA[1][0] + (size_t)(TT) * 64, (DB) + 8192); \
  stage16(gA[1][1] + (size_t)(TT) * 64, (DB) + 12288); } while (0)
#define SB_H0(TT, DB) do { \
  stage16(gB[0][0] + (size_t)(TT) * 64, (DB)); \
  stage16(gB[0][1] + (size_t)(TT) * 64, (DB) + 4096); } while (0)
#define SB_H1(TT, DB) do { \
  stage16(gB[1][0] + (size_t)(TT) * 64, (DB) + 8192); \
  stage16(gB[1][1] + (size_t)(TT) * 64, (DB) + 12288); } while (0)
// zcorr A source switches at tile 16 (h_hi from Xb, then h_lo from Hlo)
#define ZSA_H0(TT, DB) do { \
  const unsigned short *z0_, *z1_; \
  if ((TT) < 16) { z0_ = gAX[0][0] + (size_t)(TT) * 64; z1_ = gAX[0][1] + (size_t)(TT) * 64; } \
  else { z0_ = gAH[0][0] + (size_t)((TT) - 16) * 64; z1_ = gAH[0][1] + (size_t)((TT) - 16) * 64; } \
  stage16(z0_, (DB)); stage16(z1_, (DB) + 4096); } while (0)
#define ZSA_H1(TT, DB) do { \
  const unsigned short *z2_, *z3_; \
  if ((TT) < 16) { z2_ = gAX[1][0] + (size_t)(TT) * 64; z3_ = gAX[1][1] + (size_t)(TT) * 64; } \
  else { z2_ = gAH[1][0] + (size_t)((TT) - 16) * 64; z3_ = gAH[1][1] + (size_t)((TT) - 16) * 64; } \
  stage16(z2_, (DB) + 8192); stage16(z3_, (DB) + 12288); } while (0)

// 16 MFMA for output quadrant Q (acc rows 2Q, 2Q+1)
#define MFMAQ(Q, S) do { \
  __builtin_amdgcn_s_setprio(1); \
  _Pragma("unroll") \
  for (int ni = 0; ni < 4; ++ni) { \
    acc[2 * (Q)    ][ni] = __builtin_amdgcn_mfma_f32_16x16x32_bf16(S[0], bq[ni], acc[2 * (Q)    ][ni], 0, 0, 0); \
    acc[2 * (Q) + 1][ni] = __builtin_amdgcn_mfma_f32_16x16x32_bf16(S[1], bq[ni], acc[2 * (Q) + 1][ni], 0, 0, 0); \
  } \
  _Pragma("unroll") \
  for (int ni = 0; ni < 4; ++ni) { \
    acc[2 * (Q)    ][ni] = __builtin_amdgcn_mfma_f32_16x16x32_bf16(S[2], bq[4 + ni], acc[2 * (Q)    ][ni], 0, 0, 0); \
    acc[2 * (Q) + 1][ni] = __builtin_amdgcn_mfma_f32_16x16x32_bf16(S[3], bq[4 + ni], acc[2 * (Q) + 1][ni], 0, 0, 0); \
  } \
  __builtin_amdgcn_s_setprio(0); \
} while (0)

#define KTILE(CA, CB, S0, S1, S2, S3, VMX) do { \
  s16x8 bq[8], aE[4], aO[4]; \
  BH(bq, CB, 0); BH(bq, CB, 1); \
  AQ(aE, CA, 0); \
  S0; \
  LGKM8; \
  BARR; LGKM0; SB0; \
  MFMAQ(0, aE); \
  BARR; \
  AQ(aO, CA, 1); S1; \
  BARR; LGKM0; SB0; \
  MFMAQ(1, aO); \
  BARR; \
  AQ(aE, CA, 2); S2; \
  BARR; LGKM0; SB0; \
  MFMAQ(2, aE); \
  BARR; \
  AQ(aO, CA, 3); S3; \
  BARR; LGKM0; SB0; \
  MFMAQ(3, aO); \
  VMX; BARR; \
} while (0)

// Gate GEMM + fused LSTM epilogue. M=16384, N=4096 (permuted), K=1536, NT=24.
__global__ __launch_bounds__(512, 2) void gemm_gates2(const unsigned short* __restrict__ Xb,
                                                      const unsigned short* __restrict__ Wg,
                                                      const float* __restrict__ bx,
                                                      const float* __restrict__ cold,
                                                      const unsigned short* __restrict__ Dgz,
                                                      float* __restrict__ hnew,
                                                      unsigned short* __restrict__ hnewb) {
  __shared__ unsigned short lds[2][2][16384];   // 128 KiB
  const int tid = threadIdx.x;
  const int lane = tid & 63, wave = tid >> 6;
  const int wm = wave & 1, wn = wave >> 1;
  const int ln = lane & 15, qlane = lane >> 4;
  // natural mapping: bx mod 8 pins each XCD to 2 B-panels (L2-resident)
  const int n0 = blockIdx.x << 8, m0 = blockIdx.y << 8;
  const int sr = tid >> 3;
  const int j = ((tid & 7) - (sr & 7)) & 7;

  const unsigned short* gA[2][2];
  const unsigned short* gB[2][2];
#pragma unroll
  for (int hh = 0; hh < 2; ++hh)
#pragma unroll
    for (int u = 0; u < 2; ++u) {
      const int row = hh * 128 + u * 64 + sr;
      gA[hh][u] = Xb + (size_t)(m0 + row) * 1536 + j * 8;
      gB[hh][u] = Wg + (size_t)(n0 + row) * 1536 + j * 8;
    }
  unsigned short* const dA0 = &lds[0][0][0] + (tid & ~63) * 8;
  unsigned short* const dB0 = &lds[0][1][0] + (tid & ~63) * 8;
  unsigned short* const dA1 = &lds[1][0][0] + (tid & ~63) * 8;
  unsigned short* const dB1 = &lds[1][1][0] + (tid & ~63) * 8;
  const unsigned short* const lA0 = &lds[0][0][0];
  const unsigned short* const lB0 = &lds[0][1][0];
  const unsigned short* const lA1 = &lds[1][0][0];
  const unsigned short* const lB1 = &lds[1][1][0];
  const int sl0 = ((qlane + ln) & 7) * 8;
  const int sl1 = sl0 ^ 32;
  const int aoff0 = (wm * 128 + ln) * 64 + sl0;
  const int aoff1 = (wm * 128 + ln) * 64 + sl1;
  const int boff0 = (wn * 64 + ln) * 64 + sl0;
  const int boff1 = (wn * 64 + ln) * 64 + sl1;

  f32x4 acc[8][4] = {};

  // prologue: stage tiles 0 and 1 (16 loads); wait for tile 0's 8
  SA_H0(0, dA0); SA_H1(0, dA0); SB_H0(0, dB0); SB_H1(0, dB0);
  SA_H0(1, dA1); SA_H1(1, dA1); SB_H0(1, dB1); SB_H1(1, dB1);
  VM8;
  BARR;

  // tile 0: A(1),B(1) already staged; stage only B(2). End vmcnt(4) drains the
  // prologue's tile-1 loads (8), leaves B(2)'s 4 in flight.
  KTILE(lA0, lB0, NOST, NOST, SB_H0(2, dB0), SB_H1(2, dB0), VM4);
#pragma unroll 1
  for (int t = 1; t < 21; t += 2) {
    KTILE(lA1, lB1, SA_H0(t + 1, dA0), SA_H1(t + 1, dA0),
                    SB_H0(t + 2, dB1), SB_H1(t + 2, dB1), VM4);
    KTILE(lA0, lB0, SA_H0(t + 2, dA1), SA_H1(t + 2, dA1),
                    SB_H0(t + 3, dB0), SB_H1(t + 3, dB0), VM4);
  }
  KTILE(lA1, lB1, SA_H0(22, dA0), SA_H1(22, dA0),
                  SB_H0(23, dB1), SB_H1(23, dB1), VM4);             // tile 21
  KTILE(lA0, lB0, SA_H0(23, dA1), SA_H1(23, dA1), NOST, NOST, VM0); // tile 22
  KTILE(lA1, lB1, NOST, NOST, NOST, NOST, VMNONE);                  // tile 23

  // Epilogue: acc[mi][ni] is gate ni for unit = blkX*64 + wn*16 + ln.
  const int unit = ((int)blockIdx.x << 6) + (wn << 4) + ln;
  const float bi = bx[unit];
  const float bo = bx[1024 + unit];
  const float bfg = bx[2048 + unit];
  const float bz = bx[3072 + unit];
#pragma unroll
  for (int mi = 0; mi < 8; ++mi) {
#pragma unroll
    for (int r = 0; r < 4; ++r) {
      const int b = m0 + wm * 128 + mi * 16 + qlane * 4 + r;
      const int idx = b * 1024 + unit;
      const float gi = acc[mi][0][r] + bi;
      const float go = acc[mi][1][r] + bo;
      const float gf = acc[mi][2][r] + bfg;
      const float gz = acc[mi][3][r] + bz + bf2f(Dgz[idx]);
      const float iv = sigmoid_f(gi);
      const float ov = sigmoid_f(go);
      const float fv = sigmoid_f(gf);
      const float zv = tanh_f(gz);
      const float cn = iv * zv + fv * cold[idx];
      const float hn = ov * tanh_f(cn);
      hnew[idx] = hn;
      hnewb[idx] = f2bf(hn);
    }
  }
}

// Dgz[b,u] = sum_k h_hi*W_lo + h_lo*W_hi. M=16384, N=1024, K=2048, NT=32.
__global__ __launch_bounds__(512, 2) void gemm_zcorr2(const unsigned short* __restrict__ Xb,
                                                      const unsigned short* __restrict__ Hlo,
                                                      const unsigned short* __restrict__ Wz2,
                                                      unsigned short* __restrict__ Dgz) {
  __shared__ unsigned short lds[2][2][16384];
  const int tid = threadIdx.x;
  const int lane = tid & 63, wave = tid >> 6;
  const int wm = wave & 1, wn = wave >> 1;
  const int ln = lane & 15, qlane = lane >> 4;
  const int n0 = blockIdx.x << 8, m0 = blockIdx.y << 8;
  const int sr = tid >> 3;
  const int j = ((tid & 7) - (sr & 7)) & 7;

  const unsigned short* gAX[2][2];
  const unsigned short* gAH[2][2];
  const unsigned short* gB[2][2];
#pragma unroll
  for (int hh = 0; hh < 2; ++hh)
#pragma unroll
    for (int u = 0; u < 2; ++u) {
      const int row = hh * 128 + u * 64 + sr;
      gAX[hh][u] = Xb  + (size_t)(m0 + row) * 1536 + 512 + j * 8;
      gAH[hh][u] = Hlo + (size_t)(m0 + row) * 1024 + j * 8;
      gB[hh][u]  = Wz2 + (size_t)(n0 + row) * 2048 + j * 8;
    }
  unsigned short* const dA0 = &lds[0][0][0] + (tid & ~63) * 8;
  unsigned short* const dB0 = &lds[0][1][0] + (tid & ~63) * 8;
  unsigned short* const dA1 = &lds[1][0][0] + (tid & ~63) * 8;
  unsigned short* const dB1 = &lds[1][1][0] + (tid & ~63) * 8;
  const unsigned short* const lA0 = &lds[0][0][0];
  const unsigned short* const lB0 = &lds[0][1][0];
  const unsigned short* const lA1 = &lds[1][0][0];
  const unsigned short* const lB1 = &lds[1][1][0];
  const int sl0 = ((qlane + ln) & 7) * 8;
  const int sl1 = sl0 ^ 32;
  const int aoff0 = (wm * 128 + ln) * 64 + sl0;
  const int aoff1 = (wm * 128 + ln) * 64 + sl1;
  const int boff0 = (wn * 64 + ln) * 64 + sl0;
  const int boff1 = (wn * 64 + ln) * 64 + sl1;

  f32x4 acc[8][4] = {};

  ZSA_H0(0, dA0); ZSA_H1(0, dA0); SB_H0(0, dB0); SB_H1(0, dB0);
  ZSA_H0(1, dA1); ZSA_H1(1, dA1); SB_H0(1, dB1); SB_H1(1, dB1);
  VM8;
  BARR;

  KTILE(lA0, lB0, NOST, NOST, SB_H0(2, dB0), SB_H1(2, dB0), VM4);   // tile 0
#pragma unroll 1
  for (int t = 1; t < 29; t += 2) {
    KTILE(lA1, lB1, ZSA_H0(t + 1, dA0), ZSA_H1(t + 1, dA0),
                    SB_H0(t + 2, dB1), SB_H1(t + 2, dB1), VM4);
    KTILE(lA0, lB0, ZSA_H0(t + 2, dA1), ZSA_H1(t + 2, dA1),
                    SB_H0(t + 3, dB0), SB_H1(t + 3, dB0), VM4);
  }
  KTILE(lA1, lB1, ZSA_H0(30, dA0), ZSA_H1(30, dA0),
                  SB_H0(31, dB1), SB_H1(31, dB1), VM4);               // tile 29
  KTILE(lA0, lB0, ZSA_H0(31, dA1), ZSA_H1(31, dA1), NOST, NOST, VM0); // tile 30
  KTILE(lA1, lB1, NOST, NOST, NOST, NOST, VMNONE);                    // tile 31

#pragma unroll
  for (int mi = 0; mi < 8; ++mi) {
#pragma unroll
    for (int r = 0; r < 4; ++r) {
      const int b = m0 + wm * 128 + mi * 16 + qlane * 4 + r;
#pragma unroll
      for (int ni = 0; ni < 4; ++ni) {
        const int n = n0 + wn * 64 + ni * 16 + ln;
        Dgz[b * 1024 + n] = f2bf(acc[mi][ni][r]);
      }
    }
  }
}

// out = h_new @ Wout^T + bout. M=16384, N=512, K=1024.
__global__ __launch_bounds__(256) void gemm_out(const unsigned short* __restrict__ Hb,
                                                const unsigned short* __restrict__ Wo,
                                                const float* __restrict__ bout,
                                                float* __restrict__ out) {
  __shared__ unsigned short As[8192];
  __shared__ unsigned short Bs[8192];
  const int n0 = blockIdx.x * 128;
  const int m0 = blockIdx.y * 128;
  const int tid = threadIdx.x, lane = tid & 63, wave = tid >> 6;
  const unsigned short *ga[4], *gb[4];
  unsigned short *la[4], *lb[4];
#pragma unroll
  for (int u = 0; u < 4; ++u) {
    int p = u * 256 + tid;
    int r = p >> 3;
    int jj = ((p & 7) - r) & 7;
    ga[u] = Hb + (size_t)(m0 + r) * 1024 + jj * 8;
    gb[u] = Wo + (size_t)(n0 + r) * 1024 + jj * 8;
    la[u] = As + (u * 256 + (tid & ~63)) * 8;
    lb[u] = Bs + (u * 256 + (tid & ~63)) * 8;
  }
  f32x4 acc[4][4] = {};
  for (int kk = 0; kk < 16; ++kk) {
#pragma unroll
    for (int u = 0; u < 4; ++u) { stage16(ga[u], la[u]); stage16(gb[u], lb[u]); }
#pragma unroll
    for (int u = 0; u < 4; ++u) { ga[u] += 64; gb[u] += 64; }
    __syncthreads();
    mma_step64(As, Bs, acc, lane, wave);
    __syncthreads();
  }
  const int wm = wave & 1, wn = wave >> 1;
  const int ln = lane & 15, q = lane >> 4;
  float bo_[4];
#pragma unroll
  for (int ni = 0; ni < 4; ++ni) bo_[ni] = bout[n0 + wn * 64 + ni * 16 + ln];
#pragma unroll
  for (int mi = 0; mi < 4; ++mi) {
#pragma unroll
    for (int r = 0; r < 4; ++r) {
      const int b = m0 + wm * 64 + mi * 16 + q * 4 + r;
#pragma unroll
      for (int ni = 0; ni < 4; ++ni) {
        const int n = n0 + wn * 64 + ni * 16 + ln;
        out[b * 512 + n] = acc[mi][ni][r] + bo_[ni];
      }
    }
  }
}

extern "C" void kernel_launch(void* const* d_in, const int* in_sizes, int n_in,
                              void* d_out, int out_size, void* d_ws, size_t ws_size,
                              hipStream_t stream) {
  const float* inp  = (const float*)d_in[0];
  const float* h    = (const float*)d_in[1];
  const float* c    = (const float*)d_in[2];
  const float* Wx   = (const float*)d_in[3];
  const float* bx   = (const float*)d_in[4];
  const float* Wh   = (const float*)d_in[5];
  const float* Wout = (const float*)d_in[6];
  const float* bout = (const float*)d_in[7];

  float* out  = (float*)d_out;                       // [B, 512]
  float* hnew = out + (size_t)BB * OO;               // [B, 1024]

  char* ws = (char*)d_ws;
  unsigned short* Xb  = (unsigned short*)(ws);                  //  50,331,648 B
  unsigned short* Wg  = (unsigned short*)(ws + 50331648);       //  12,582,912 B
  unsigned short* Wo  = (unsigned short*)(ws + 62914560);       //   1,048,576 B
  unsigned short* Hb  = (unsigned short*)(ws + 63963136);       //  33,554,432 B
  unsigned short* Hlo = (unsigned short*)(ws + 97517568);       //  33,554,432 B
  unsigned short* Wz2 = (unsigned short*)(ws + 131072000);      //   4,194,304 B
  unsigned short* Dgz = (unsigned short*)(ws + 135266304);      //  33,554,432 B

  prep_all<<<16640, 256, 0, stream>>>(inp, h, Wx, Wh, Wout, Xb, Hlo, Wg, Wz2, Wo);
  gemm_zcorr2<<<dim3(4, 64),  512, 0, stream>>>(Xb, Hlo, Wz2, Dgz);
  gemm_gates2<<<dim3(16, 64), 512, 0, stream>>>(Xb, Wg, bx, c, Dgz, hnew, Hb);
  gemm_out  <<<dim3(4, 128),  256, 0, stream>>>(Hb, Wo, bout, out);
}